// Round 17
// baseline (575.981 us; speedup 1.0000x reference)
//
#include <hip/hip_runtime.h>
#include <hip/hip_bf16.h>

typedef __hip_bfloat16 bf16;
typedef __attribute__((ext_vector_type(8))) short short8;
typedef __attribute__((ext_vector_type(4))) float f32x4;

#define MODEL_DIM 2048
#define INNER     4096
#define NHEADS    64
#define HEAD_DIM  64
#define STATE_DIM 128
#define IN_PROJ   4416        /* = 23*192: BN=192 tiles need NO padding */
#define BSZ       2
#define SEQ       4096
#define CHUNKL    64
#define NTOK      (BSZ*SEQ)      /* 8192 */
#define NCHUNK    (SEQ/CHUNKL)   /* 64 */

/* merged-convert range boundaries (in float4 units) */
#define CN1 (NTOK * MODEL_DIM / 4)
#define CN2 (CN1 + IN_PROJ * MODEL_DIM / 4)
#define CN3 (CN2 + MODEL_DIM * INNER / 4)

#define WAITV0() asm volatile("s_waitcnt vmcnt(0)" ::: "memory")
#define BAR()    __builtin_amdgcn_s_barrier()
#define SCHEDB() __builtin_amdgcn_sched_barrier(0)
#define WAITLG(N) do { asm volatile("s_waitcnt lgkmcnt(" #N ")" ::: "memory"); SCHEDB(); } while (0)

// swizzle: XOR the 16B-slot index (bits 4-6) with row&7 (bits 7-9). Involution.
#define SWZ(x) ((x) ^ ((((x) >> 7) & 7) << 4))

// ---------------- helpers ----------------
static __device__ __forceinline__ void gload_lds16(const bf16* g, bf16* l) {
  __builtin_amdgcn_global_load_lds((const __attribute__((address_space(1))) void*)g,
                                   (__attribute__((address_space(3))) void*)l, 16, 0, 0);
}

static __device__ __forceinline__ unsigned lds_u32(const void* p) {
  return (unsigned)(unsigned long long)(const __attribute__((address_space(3))) char*)p;
}

static __device__ __forceinline__ short8 ds_read128(unsigned addr) {
  short8 r;
  asm volatile("ds_read_b128 %0, %1" : "=v"(r) : "v"(addr));
  return r;
}

// stage one 8KB unit (64 rows x 64 cols bf16): 1 gload_lds per thread (512 thr x 16B).
static __device__ __forceinline__ void stage_unit(const bf16* __restrict__ P, int K,
                                                  int blockRow, int kt,
                                                  char* region, int unit, int t) {
  int o = unit * 8192 + (t << 4);
  int lb = SWZ(o);
  int row = lb >> 7, colb = lb & 127;
  gload_lds16(P + (size_t)(blockRow + row) * K + kt + (colb >> 1), (bf16*)(region + o));
}

#define MFMA_BLK(MLO, MHI, NLO, NHI)                                                    \
  __builtin_amdgcn_s_setprio(1);                                                       \
  _Pragma("unroll") for (int mf = (MLO); mf < (MHI); ++mf)                             \
    _Pragma("unroll") for (int nf = (NLO); nf < (NHI); ++nf)                           \
      _Pragma("unroll") for (int ks = 0; ks < 2; ++ks)                                 \
        acc[mf][nf] = __builtin_amdgcn_mfma_f32_16x16x32_bf16(a[mf][ks], b[nf][ks],    \
                                                              acc[mf][nf], 0, 0, 0);  \
  __builtin_amdgcn_s_setprio(0);

// ---------------- 256xBN / BK=64 / 8-wave / counted-lgkm GEMM core (R8, best) ----------------
template<int BN>
static __device__ __forceinline__ void gemm_core1(
    const bf16* __restrict__ Ag, const bf16* __restrict__ Bg,
    int K, int NT, int bm, int bn, char* lds, f32x4 (&acc)[8][BN / 64]) {
  constexpr int NR = BN / 64;
  constexpr int BB = 32768 + NR * 8192;
  const int t = threadIdx.x;
  const int lane = t & 63;
  const int wid = t >> 6, wm = wid >> 2, wn = wid & 3;
  const unsigned x16 = (unsigned)(lane & 7) << 4;
  const unsigned kb0 = (unsigned)(lane >> 4) << 4;
  const unsigned ldsB = lds_u32(lds);
  const unsigned aRow0 = (unsigned)(wm * 128 + (lane & 15)) * 128;
  const unsigned bRow0 = (unsigned)(wn * (BN / 4) + (lane & 15)) * 128;

#pragma unroll
  for (int u = 0; u < 4; ++u) stage_unit(Ag, K, bm, 0, lds, u, t);
#pragma unroll
  for (int u = 0; u < NR; ++u) stage_unit(Bg, K, bn, 0, lds + 32768, u, t);
  WAITV0();
  BAR();

  int cur = 0;
  for (int tt = 0; tt < NT; ++tt) {
    char* oth = lds + (cur ^ 1) * BB;
    const unsigned aB = ldsB + (unsigned)(cur * BB);
    const unsigned bB = aB + 32768;
    const bool st = (tt + 1 < NT);

    if (st) {
      const int kt1 = (tt + 1) * 64;
#pragma unroll
      for (int u = 0; u < 4; ++u) stage_unit(Ag, K, bm, kt1, oth, u, t);
#pragma unroll
      for (int u = 0; u < NR; ++u) stage_unit(Bg, K, bn, kt1, oth + 32768, u, t);
    }

    short8 a[8][2], b[NR][2];
#pragma unroll
    for (int mf = 0; mf < 4; ++mf)
#pragma unroll
      for (int ks = 0; ks < 2; ++ks)
        a[mf][ks] = ds_read128(aB + aRow0 + mf * 2048 + (((unsigned)(ks * 64) + kb0) ^ x16));
#pragma unroll
    for (int nf = 0; nf < 2; ++nf)
#pragma unroll
      for (int ks = 0; ks < 2; ++ks)
        b[nf][ks] = ds_read128(bB + bRow0 + nf * 2048 + (((unsigned)(ks * 64) + kb0) ^ x16));
#pragma unroll
    for (int mf = 4; mf < 8; ++mf)
#pragma unroll
      for (int ks = 0; ks < 2; ++ks)
        a[mf][ks] = ds_read128(aB + aRow0 + mf * 2048 + (((unsigned)(ks * 64) + kb0) ^ x16));
#pragma unroll
    for (int nf = 2; nf < NR; ++nf)
#pragma unroll
      for (int ks = 0; ks < 2; ++ks)
        b[nf][ks] = ds_read128(bB + bRow0 + nf * 2048 + (((unsigned)(ks * 64) + kb0) ^ x16));

    if constexpr (NR == 4) WAITLG(12); else WAITLG(10);
    MFMA_BLK(0, 4, 0, 2);
    if constexpr (NR == 4) WAITLG(4);  else WAITLG(2);
    MFMA_BLK(4, 8, 0, 2);
    WAITLG(0);
    MFMA_BLK(0, 8, 2, NR);

    if (st) WAITV0();
    BAR();
    cur ^= 1;
  }
}

// in-proj GEMM (BN=192, N=4416 exact): routed epilogue with fused dt tables
__global__ __launch_bounds__(512, 2)
void gemm_in256(const bf16* __restrict__ A, const bf16* __restrict__ Bw,
                const float* __restrict__ bias, bf16* __restrict__ x_bf,
                bf16* __restrict__ B_bf, bf16* __restrict__ C_bf,
                const float* __restrict__ A_log, const float* __restrict__ dt_bias,
                float* __restrict__ dts, float* __restrict__ a_dt) {
  __shared__ char lds[2 * (32768 + 3 * 8192)];
  int nwg = gridDim.x, bid = blockIdx.x;
  int cpx = nwg >> 3;
  int sb = (bid & 7) * cpx + (bid >> 3);       // bijective: nwg % 8 == 0
  int bx = sb % (IN_PROJ / 192), by = sb / (IN_PROJ / 192);
  int bm = by * 256, bn = bx * 192;
  f32x4 acc[8][3] = {};
  gemm_core1<192>(A, Bw, MODEL_DIM, MODEL_DIM / 64, bm, bn, lds, acc);
  const int lane = threadIdx.x & 63, wid = threadIdx.x >> 6;
  const int wm = wid >> 2, wn = wid & 3;
#pragma unroll
  for (int mf = 0; mf < 8; ++mf)
#pragma unroll
    for (int nf = 0; nf < 3; ++nf)
#pragma unroll
      for (int r = 0; r < 4; ++r) {
        int row = bm + wm * 128 + mf * 16 + (lane >> 4) * 4 + r;
        int col = bn + wn * 48 + nf * 16 + (lane & 15);
        float v = acc[mf][nf][r] + bias[col];
        if (col < 4096)       x_bf[(size_t)row * 4096 + col]         = __float2bfloat16(v);
        else if (col < 4224)  B_bf[(size_t)row * 128 + (col - 4096)] = __float2bfloat16(v);
        else if (col < 4352)  C_bf[(size_t)row * 128 + (col - 4224)] = __float2bfloat16(v);
        else {                                   // fused softplus + a_dt tables
          int hh = col - 4352;
          float z = v + dt_bias[hh];
          float dt = (z > 20.f) ? z : log1pf(expf(z));
          dts[(size_t)row * 64 + hh] = dt;
          a_dt[(size_t)row * 64 + hh] = -expf(A_log[hh]) * dt;
        }
      }
}

// out-proj GEMM (BN=256): f32 output + bias
__global__ __launch_bounds__(512, 2)
void gemm_out256(const bf16* __restrict__ A, const bf16* __restrict__ Bw,
                 const float* __restrict__ bias, float* __restrict__ C) {
  __shared__ char lds[2 * (32768 + 4 * 8192)];
  int nwg = gridDim.x, bid = blockIdx.x;
  int cpx = nwg >> 3;
  int sb = (bid & 7) * cpx + (bid >> 3);
  int bx = sb % (MODEL_DIM / 256), by = sb / (MODEL_DIM / 256);
  int bm = by * 256, bn = bx * 256;
  f32x4 acc[8][4] = {};
  gemm_core1<256>(A, Bw, INNER, INNER / 64, bm, bn, lds, acc);
  const int lane = threadIdx.x & 63, wid = threadIdx.x >> 6;
  const int wm = wid >> 2, wn = wid & 3;
#pragma unroll
  for (int mf = 0; mf < 8; ++mf)
#pragma unroll
    for (int nf = 0; nf < 4; ++nf)
#pragma unroll
      for (int r = 0; r < 4; ++r) {
        int row = bm + wm * 128 + mf * 16 + (lane >> 4) * 4 + r;
        int col = bn + wn * 64 + nf * 16 + (lane & 15);
        C[(size_t)row * MODEL_DIM + col] = acc[mf][nf][r] + bias[col];
      }
}

// ---------------- merged convert: u, W_in, W_out in one dispatch ----------------
__global__ __launch_bounds__(256)
void conv_all(const float* __restrict__ u, const float* __restrict__ Win,
              const float* __restrict__ Wout, bf16* __restrict__ u_bf,
              bf16* __restrict__ win_bf, bf16* __restrict__ wout_bf) {
  int i = blockIdx.x * 256 + threadIdx.x;
  const float* s; bf16* d; int j;
  if (i < CN1)      { s = u;    d = u_bf;    j = i; }
  else if (i < CN2) { s = Win;  d = win_bf;  j = i - CN1; }
  else if (i < CN3) { s = Wout; d = wout_bf; j = i - CN2; }
  else return;
  float4 v = *(const float4*)(s + (size_t)j * 4);
  bf16* p = d + (size_t)j * 4;
  p[0] = __float2bfloat16(v.x); p[1] = __float2bfloat16(v.y);
  p[2] = __float2bfloat16(v.z); p[3] = __float2bfloat16(v.w);
}

// ---------------- g_pre: G = C * B^T per (b,c), head-independent ----------------
__global__ __launch_bounds__(256)
void g_pre_kernel(const bf16* __restrict__ B_bf, const bf16* __restrict__ C_bf,
                  float* __restrict__ G_g) {
  __shared__ bf16 Cs[64 * 128];
  __shared__ bf16 Bs[64 * 128];
  int blk = blockIdx.x;             // b*64 + c
  int t = threadIdx.x, lane = t & 63, wid = t >> 6;
  int tokBase = (blk >> 6) * SEQ + (blk & 63) * 64;

#pragma unroll
  for (int i = 0; i < 4; ++i) {
    int chunk = t + i * 256;
    int l = chunk >> 4, n0 = (chunk & 15) * 8;
    *(short8*)(Cs + l * 128 + n0) = *(const short8*)(C_bf + (size_t)(tokBase + l) * 128 + n0);
    *(short8*)(Bs + l * 128 + n0) = *(const short8*)(B_bf + (size_t)(tokBase + l) * 128 + n0);
  }
  __syncthreads();

  int lBase = (wid >> 1) * 32, sBase = (wid & 1) * 32;
  f32x4 g[2][2] = {};
#pragma unroll
  for (int ks = 0; ks < 4; ++ks) {
    short8 a[2], bb[2];
#pragma unroll
    for (int mi = 0; mi < 2; ++mi)
      a[mi] = *(const short8*)(Cs + (lBase + mi * 16 + (lane & 15)) * 128 + ks * 32 + (lane >> 4) * 8);
#pragma unroll
    for (int ni = 0; ni < 2; ++ni)
      bb[ni] = *(const short8*)(Bs + (sBase + ni * 16 + (lane & 15)) * 128 + ks * 32 + (lane >> 4) * 8);
#pragma unroll
    for (int mi = 0; mi < 2; ++mi)
#pragma unroll
      for (int ni = 0; ni < 2; ++ni)
        g[mi][ni] = __builtin_amdgcn_mfma_f32_16x16x32_bf16(a[mi], bb[ni], g[mi][ni], 0, 0, 0);
  }
  float* Gd = G_g + (size_t)blk * 4096;
#pragma unroll
  for (int mi = 0; mi < 2; ++mi)
#pragma unroll
    for (int ni = 0; ni < 2; ++ni)
#pragma unroll
      for (int r = 0; r < 4; ++r) {
        int row = lBase + mi * 16 + (lane >> 4) * 4 + r;
        int col = sBase + ni * 16 + (lane & 15);
        Gd[row * 64 + col] = g[mi][ni][r];
      }
}

// ---------------- FUSED intra-chunk states + inter-chunk scan (1-sync pipeline) ----------------
#define LP 72   /* padded LDS row length */
__global__ __launch_bounds__(256)
void ssd_fused_kernel(const bf16* __restrict__ x_bf, const bf16* __restrict__ B_bf,
                      const float* __restrict__ dts_g, const float* __restrict__ a_dt,
                      float* __restrict__ acs_g, bf16* __restrict__ states_g,
                      float* __restrict__ out_fs) {
  __shared__ bf16 xT[2][32 * LP];
  __shared__ bf16 BT[2][128 * LP];
  __shared__ float sc_s[2][64];     // dt*decay scale per token; ring by chunk parity (pre-phase only)
  __shared__ float dfac_s[4];       // depth-4 ring: pre(c) write crosses to post(c) read
  int blk = blockIdx.x;
  int pg = blk & 1, h = (blk >> 1) & 63, b = blk >> 7;
  int t = threadIdx.x, lane = t & 63, w = t >> 6;
  int lx = t >> 2, sx = t & 3;

  f32x4 S4[4] = {};
  short8 rxC, rBC[4], rxN, rBN[4];
  float raN = 0.f, rdtN = 0.f;

  // prologue: chunk 0 data + cumsum(0); chunk 1 data
  {
    int tb = b * SEQ;
    rxC = *(const short8*)(x_bf + (size_t)(tb + lx) * 4096 + h * 64 + pg * 32 + sx * 8);
#pragma unroll
    for (int k = 0; k < 4; ++k)
      rBC[k] = *(const short8*)(B_bf + (size_t)(tb + lx) * 128 + sx * 32 + k * 8);
    if (t < 64) {
      float ra0 = a_dt[(size_t)(tb + t) * 64 + h];
      float rdt0 = dts_g[(size_t)(tb + t) * 64 + h];
      float v = ra0;
#pragma unroll
      for (int d = 1; d < 64; d <<= 1) { float o = __shfl_up(v, d); if (t >= d) v += o; }
      float a63 = __shfl(v, 63);
      if (pg == 0) acs_g[(((size_t)(b * 64 + 0)) * 64 + h) * 64 + t] = v;
      sc_s[0][t] = rdt0 * expf(a63 - v);
      if (t == 0) dfac_s[0] = expf(a63);
    }
    int tb1 = tb + 64;
    rxN = *(const short8*)(x_bf + (size_t)(tb1 + lx) * 4096 + h * 64 + pg * 32 + sx * 8);
#pragma unroll
    for (int k = 0; k < 4; ++k)
      rBN[k] = *(const short8*)(B_bf + (size_t)(tb1 + lx) * 128 + sx * 32 + k * 8);
    if (t < 64) {
      raN = a_dt[(size_t)(tb1 + t) * 64 + h];
      rdtN = dts_g[(size_t)(tb1 + t) * 64 + h];
    }
  }
  __syncthreads();

  for (int c = 0; c < 64; ++c) {
    // issue loads for c+2 (clamped; unused duplicates at the tail)
    int c2 = (c < 62) ? c + 2 : 63;
    int tb2 = b * SEQ + c2 * 64;
    short8 rxI = *(const short8*)(x_bf + (size_t)(tb2 + lx) * 4096 + h * 64 + pg * 32 + sx * 8);
    short8 rBI[4];
#pragma unroll
    for (int k = 0; k < 4; ++k)
      rBI[k] = *(const short8*)(B_bf + (size_t)(tb2 + lx) * 128 + sx * 32 + k * 8);
    float raI = 0.f, rdtI = 0.f;
    if (t < 64) {
      raI = a_dt[(size_t)(tb2 + t) * 64 + h];
      rdtI = dts_g[(size_t)(tb2 + t) * 64 + h];
    }

    int bufc = c & 1;
    // pre: transpose(c) with sc_s[c&1]; wave-0 lanes also cumsum(c+1)
    {
      float s_l = sc_s[bufc][lx];
      const bf16* pv = (const bf16*)&rxC;
#pragma unroll
      for (int j = 0; j < 8; ++j)
        xT[bufc][(sx * 8 + j) * LP + lx] = __float2bfloat16(__bfloat162float(pv[j]) * s_l);
#pragma unroll
      for (int k = 0; k < 4; ++k) {
        const bf16* pb = (const bf16*)&rBC[k];
        int n0 = sx * 32 + k * 8;
#pragma unroll
        for (int j = 0; j < 8; ++j) BT[bufc][(n0 + j) * LP + lx] = pb[j];
      }
    }
    if (t < 64) {
      float v = raN;
#pragma unroll
      for (int d = 1; d < 64; d <<= 1) { float o = __shfl_up(v, d); if (t >= d) v += o; }
      float a63 = __shfl(v, 63);
      if (c + 1 < 64 && pg == 0)
        acs_g[(((size_t)(b * 64 + c + 1)) * 64 + h) * 64 + t] = v;
      sc_s[(c + 1) & 1][t] = rdtN * expf(a63 - v);
      if (t == 0) dfac_s[(c + 1) & 3] = expf(a63);
    }
    __syncthreads();

    // post: MFMA(c) + in-register scan + states write
    float dfac = dfac_s[c & 3];
    int ps = (w >> 1) * 16, nb = (w & 1) * 64;
    f32x4 acc[4] = {};
    short8 af[2];
#pragma unroll
    for (int ks = 0; ks < 2; ++ks)
      af[ks] = *(const short8*)(&xT[bufc][(ps + (lane & 15)) * LP + ks * 32 + (lane >> 4) * 8]);
#pragma unroll
    for (int nf = 0; nf < 4; ++nf)
#pragma unroll
      for (int ks = 0; ks < 2; ++ks) {
        short8 bf_ = *(const short8*)(&BT[bufc][(nb + nf * 16 + (lane & 15)) * LP + ks * 32 + (lane >> 4) * 8]);
        acc[nf] = __builtin_amdgcn_mfma_f32_16x16x32_bf16(af[ks], bf_, acc[nf], 0, 0, 0);
      }
    size_t sbase = ((size_t)((b * 64 + c) * 64 + h)) * 8192;
#pragma unroll
    for (int nf = 0; nf < 4; ++nf)
#pragma unroll
      for (int r = 0; r < 4; ++r) {
        int p = pg * 32 + ps + (lane >> 4) * 4 + r;
        int n = nb + nf * 16 + (lane & 15);
        states_g[sbase + (size_t)p * 128 + n] = __float2bfloat16(S4[nf][r]);
        S4[nf][r] = dfac * S4[nf][r] + acc[nf][r];
      }

    rxC = rxN; rxN = rxI;
#pragma unroll
    for (int k = 0; k < 4; ++k) { rBC[k] = rBN[k]; rBN[k] = rBI[k]; }
    raN = raI; rdtN = rdtI;
  }

  size_t ob = ((size_t)(b * 64 + h)) * 8192;
  int ps = (w >> 1) * 16, nb = (w & 1) * 64;
#pragma unroll
  for (int nf = 0; nf < 4; ++nf)
#pragma unroll
    for (int r = 0; r < 4; ++r) {
      int p = pg * 32 + ps + (lane >> 4) * 4 + r;
      int n = nb + nf * 16 + (lane & 15);
      out_fs[ob + (size_t)p * 128 + n] = S4[nf][r];
    }
}

// ---------------- output: 4 heads per block; C + G staged/loaded once ----------------
__global__ __launch_bounds__(256)
void ssd_out_kernel(bf16* __restrict__ x_bf, const bf16* __restrict__ C_bf,
                    const float* __restrict__ dts, const float* __restrict__ acs_g,
                    const bf16* __restrict__ states_g, const float* __restrict__ G_g) {
  __shared__ bf16 Cs[64 * 128];     // [l][n] (head-independent)
  __shared__ bf16 Ms[64 * 64];      // masked scores [l][s]
  __shared__ bf16 xT[64 * 64];      // [p][l]
  __shared__ bf16 Sp[64 * 128];     // [p][n]
  __shared__ float acs_s[2][64];    // double-buffered by head parity
  int blk = blockIdx.x;             // (b*64 + c)*16 + hg
  int hg = blk & 15, c = (blk >> 4) & 63, b = blk >> 10;
  int t = threadIdx.x, lane = t & 63, wid = t >> 6;
  int tokBase = b * SEQ + c * 64;

  int lBase = (wid >> 1) * 32, sBase = (wid & 1) * 32;
  // G: head-independent — load once
  const float* Gd = G_g + ((size_t)(b * 64 + c)) * 4096;
  float gv[2][2][4];
#pragma unroll
  for (int mi = 0; mi < 2; ++mi)
#pragma unroll
    for (int ni = 0; ni < 2; ++ni)
#pragma unroll
      for (int r = 0; r < 4; ++r)
        gv[mi][ni][r] = Gd[(lBase + mi * 16 + (lane >> 4) * 4 + r) * 64 +
                           sBase + ni * 16 + (lane & 15)];

  // C: head-independent — stage once
#pragma unroll
  for (int i = 0; i < 4; ++i) {
    int chunk = t + i * 256;
    int l = chunk >> 4, n0 = (chunk & 15) * 8;
    *(short8*)(Cs + l * 128 + n0) = *(const short8*)(C_bf + (size_t)(tokBase + l) * 128 + n0);
  }

  for (int hi = 0; hi < 4; ++hi) {
    int h = hg * 4 + hi;
    size_t sbase = ((size_t)((b * 64 + c) * 64 + h)) * 8192;

    // stage head-specific: acs, xT (dt-scaled), Sp
    if (t < 64) acs_s[hi & 1][t] = acs_g[(((size_t)(b * 64 + c)) * 64 + h) * 64 + t];
#pragma unroll
    for (int i = 0; i < 2; ++i) {
      int chunk = t + i * 256;
      int l = chunk >> 3, p0 = (chunk & 7) * 8;
      float dtv = dts[(size_t)(tokBase + l) * 64 + h];
      short8 vv = *(const short8*)(x_bf + (size_t)(tokBase + l) * 4096 + h * 64 + p0);
      const bf16* pv = (const bf16*)&vv;
#pragma unroll
      for (int j = 0; j < 8; ++j)
        xT[(p0 + j) * 64 + l] = __float2bfloat16(__bfloat162float(pv[j]) * dtv);
    }
#pragma unroll
    for (int i = 0; i < 4; ++i) {
      int chunk = t + i * 256;
      *(short8*)(Sp + chunk * 8) = *(const short8*)(states_g + sbase + chunk * 8);
    }
    __syncthreads();                 // sync_a: stages visible (covers Cs/G on hi==0)

    // masked scores from precomputed G
#pragma unroll
    for (int mi = 0; mi < 2; ++mi)
#pragma unroll
      for (int ni = 0; ni < 2; ++ni)
#pragma unroll
        for (int r = 0; r < 4; ++r) {
          int row = lBase + mi * 16 + (lane >> 4) * 4 + r;
          int col = sBase + ni * 16 + (lane & 15);
          float lm = (row >= col) ? expf(acs_s[hi & 1][row] - acs_s[hi & 1][col]) : 0.f;
          Ms[row * 64 + col] = __float2bfloat16(gv[mi][ni][r] * lm);
        }
    __syncthreads();                 // sync_b: Ms visible

    int pBase = (wid & 1) * 32;
    f32x4 yd[2][2] = {}, yo[2][2] = {};
#pragma unroll
    for (int ks = 0; ks < 2; ++ks) {
      short8 a[2], bb[2];
#pragma unroll
      for (int mi = 0; mi < 2; ++mi)
        a[mi] = *(const short8*)(Ms + (lBase + mi * 16 + (lane & 15)) * 64 + ks * 32 + (lane >> 4) * 8);
#pragma unroll
      for (int ni = 0; ni < 2; ++ni)
        bb[ni] = *(const short8*)(xT + (pBase + ni * 16 + (lane & 15)) * 64 + ks * 32 + (lane >> 4) * 8);
#pragma unroll
      for (int mi = 0; mi < 2; ++mi)
#pragma unroll
        for (int ni = 0; ni < 2; ++ni)
          yd[mi][ni] = __builtin_amdgcn_mfma_f32_16x16x32_bf16(a[mi], bb[ni], yd[mi][ni], 0, 0, 0);
    }
#pragma unroll
    for (int ks = 0; ks < 4; ++ks) {
      short8 a[2], bb[2];
#pragma unroll
      for (int mi = 0; mi < 2; ++mi)
        a[mi] = *(const short8*)(Cs + (lBase + mi * 16 + (lane & 15)) * 128 + ks * 32 + (lane >> 4) * 8);
#pragma unroll
      for (int ni = 0; ni < 2; ++ni)
        bb[ni] = *(const short8*)(Sp + (pBase + ni * 16 + (lane & 15)) * 128 + ks * 32 + (lane >> 4) * 8);
#pragma unroll
      for (int mi = 0; mi < 2; ++mi)
#pragma unroll
        for (int ni = 0; ni < 2; ++ni)
          yo[mi][ni] = __builtin_amdgcn_mfma_f32_16x16x32_bf16(a[mi], bb[ni], yo[mi][ni], 0, 0, 0);
    }
    __syncthreads();                 // sync_c: all LDS reads of this head done

    // write y in place (uses acs_s[hi&1]; next head stages acs_s[(hi+1)&1])
#pragma unroll
    for (int mi = 0; mi < 2; ++mi)
#pragma unroll
      for (int ni = 0; ni < 2; ++ni)
#pragma unroll
        for (int r = 0; r < 4; ++r) {
          int lr = lBase + mi * 16 + (lane >> 4) * 4 + r;
          int p = pBase + ni * 16 + (lane & 15);
          float val = yd[mi][ni][r] + expf(acs_s[hi & 1][lr]) * yo[mi][ni][r];
          x_bf[(size_t)(tokBase + lr) * 4096 + h * 64 + p] = __float2bfloat16(val);
        }
  }
}

// ---------------- launch ----------------
extern "C" void kernel_launch(void* const* d_in, const int* in_sizes, int n_in,
                              void* d_out, int out_size, void* d_ws, size_t ws_size,
                              hipStream_t stream) {
  const float* u       = (const float*)d_in[0];
  const float* W_in    = (const float*)d_in[1];
  const float* b_in    = (const float*)d_in[2];
  const float* W_out   = (const float*)d_in[3];
  const float* b_out   = (const float*)d_in[4];
  const float* A_log   = (const float*)d_in[5];
  const float* dt_bias = (const float*)d_in[6];

  float* y_out  = (float*)d_out;
  float* fs_out = y_out + (size_t)NTOK * MODEL_DIM;

  char* ws = (char*)d_ws;
  size_t off = 0;
  auto alloc = [&](size_t bytes) { char* p = ws + off; off += (bytes + 255) & ~255ull; return p; };
  bf16*  wout_bf = (bf16*) alloc((size_t)MODEL_DIM * INNER * 2);   // 16.8 MB
  bf16*  x_bf    = (bf16*) alloc((size_t)NTOK * INNER * 2);        // 67 MB (x, then y)
  bf16*  B_bf    = (bf16*) alloc((size_t)NTOK * STATE_DIM * 2);
  bf16*  C_bf    = (bf16*) alloc((size_t)NTOK * STATE_DIM * 2);
  float* dts     = (float*)alloc((size_t)NTOK * NHEADS * 4);
  float* a_dt    = (float*)alloc((size_t)NTOK * NHEADS * 4);
  float* acs     = (float*)alloc((size_t)BSZ * NCHUNK * NHEADS * 64 * 4);
  float* gbuf    = (float*)alloc((size_t)BSZ * NCHUNK * 4096 * 4); // 2 MB
  // region Q: states (bf16, 134 MB) aliased with {u_bf, win_bf} (dead after gemm_in)
  char*  Q       = alloc((size_t)BSZ * NCHUNK * NHEADS * 64 * 128 * 2);
  bf16*  states  = (bf16*)Q;
  bf16*  u_bf    = (bf16*)Q;
  bf16*  win_bf  = u_bf + (size_t)NTOK * MODEL_DIM;
  (void)ws_size; (void)off; (void)in_sizes; (void)n_in; (void)out_size;

  conv_all<<<dim3((CN3 + 255) / 256), dim3(256), 0, stream>>>(
      u, W_in, W_out, u_bf, win_bf, wout_bf);

  gemm_in256<<<dim3((NTOK / 256) * (IN_PROJ / 192)), dim3(512), 0, stream>>>(
      u_bf, win_bf, b_in, x_bf, B_bf, C_bf, A_log, dt_bias, dts, a_dt);

  g_pre_kernel<<<dim3(BSZ * NCHUNK), dim3(256), 0, stream>>>(B_bf, C_bf, gbuf);

  ssd_fused_kernel<<<dim3(BSZ * NHEADS * 2), dim3(256), 0, stream>>>(
      x_bf, B_bf, dts, a_dt, acs, states, fs_out);

  ssd_out_kernel<<<dim3(BSZ * NCHUNK * 16), dim3(256), 0, stream>>>(
      x_bf, C_bf, dts, acs, states, gbuf);

  gemm_out256<<<dim3((MODEL_DIM / 256) * (NTOK / 256)), dim3(512), 0, stream>>>(
      x_bf, wout_bf, b_out, y_out);
}

// Round 18
// 486.441 us; speedup vs baseline: 1.1841x; 1.1841x over previous
//
#include <hip/hip_runtime.h>
#include <hip/hip_bf16.h>

typedef __hip_bfloat16 bf16;
typedef __attribute__((ext_vector_type(8))) short short8;
typedef __attribute__((ext_vector_type(4))) float f32x4;

#define MODEL_DIM 2048
#define INNER     4096
#define NHEADS    64
#define HEAD_DIM  64
#define STATE_DIM 128
#define IN_PROJ   4416        /* = 23*192: BN=192 tiles need NO padding */
#define BSZ       2
#define SEQ       4096
#define CHUNKL    64
#define NTOK      (BSZ*SEQ)      /* 8192 */
#define NCHUNK    (SEQ/CHUNKL)   /* 64 */

#define WAITV0() asm volatile("s_waitcnt vmcnt(0)" ::: "memory")
#define BAR()    __builtin_amdgcn_s_barrier()
#define SCHEDB() __builtin_amdgcn_sched_barrier(0)
#define WAITLG(N) do { asm volatile("s_waitcnt lgkmcnt(" #N ")" ::: "memory"); SCHEDB(); } while (0)

// swizzle: XOR the 16B-slot index (bits 4-6) with row&7 (bits 7-9). Involution.
#define SWZ(x) ((x) ^ ((((x) >> 7) & 7) << 4))

// ---------------- helpers ----------------
static __device__ __forceinline__ void gload_lds16(const bf16* g, bf16* l) {
  __builtin_amdgcn_global_load_lds((const __attribute__((address_space(1))) void*)g,
                                   (__attribute__((address_space(3))) void*)l, 16, 0, 0);
}

static __device__ __forceinline__ unsigned lds_u32(const void* p) {
  return (unsigned)(unsigned long long)(const __attribute__((address_space(3))) char*)p;
}

static __device__ __forceinline__ short8 ds_read128(unsigned addr) {
  short8 r;
  asm volatile("ds_read_b128 %0, %1" : "=v"(r) : "v"(addr));
  return r;
}

// stage one 8KB unit (64 rows x 64 cols bf16): 1 gload_lds per thread (512 thr x 16B).
static __device__ __forceinline__ void stage_unit(const bf16* __restrict__ P, int K,
                                                  int blockRow, int kt,
                                                  char* region, int unit, int t) {
  int o = unit * 8192 + (t << 4);
  int lb = SWZ(o);
  int row = lb >> 7, colb = lb & 127;
  gload_lds16(P + (size_t)(blockRow + row) * K + kt + (colb >> 1), (bf16*)(region + o));
}

#define MFMA_BLK(MLO, MHI, NLO, NHI)                                                    \
  __builtin_amdgcn_s_setprio(1);                                                       \
  _Pragma("unroll") for (int mf = (MLO); mf < (MHI); ++mf)                             \
    _Pragma("unroll") for (int nf = (NLO); nf < (NHI); ++nf)                           \
      _Pragma("unroll") for (int ks = 0; ks < 2; ++ks)                                 \
        acc[mf][nf] = __builtin_amdgcn_mfma_f32_16x16x32_bf16(a[mf][ks], b[nf][ks],    \
                                                              acc[mf][nf], 0, 0, 0);  \
  __builtin_amdgcn_s_setprio(0);

// ---------------- 256xBN / BK=64 / 8-wave / counted-lgkm GEMM core (R8, best) ----------------
template<int BN>
static __device__ __forceinline__ void gemm_core1(
    const bf16* __restrict__ Ag, const bf16* __restrict__ Bg,
    int K, int NT, int bm, int bn, char* lds, f32x4 (&acc)[8][BN / 64]) {
  constexpr int NR = BN / 64;
  constexpr int BB = 32768 + NR * 8192;
  const int t = threadIdx.x;
  const int lane = t & 63;
  const int wid = t >> 6, wm = wid >> 2, wn = wid & 3;
  const unsigned x16 = (unsigned)(lane & 7) << 4;
  const unsigned kb0 = (unsigned)(lane >> 4) << 4;
  const unsigned ldsB = lds_u32(lds);
  const unsigned aRow0 = (unsigned)(wm * 128 + (lane & 15)) * 128;
  const unsigned bRow0 = (unsigned)(wn * (BN / 4) + (lane & 15)) * 128;

#pragma unroll
  for (int u = 0; u < 4; ++u) stage_unit(Ag, K, bm, 0, lds, u, t);
#pragma unroll
  for (int u = 0; u < NR; ++u) stage_unit(Bg, K, bn, 0, lds + 32768, u, t);
  WAITV0();
  BAR();

  int cur = 0;
  for (int tt = 0; tt < NT; ++tt) {
    char* oth = lds + (cur ^ 1) * BB;
    const unsigned aB = ldsB + (unsigned)(cur * BB);
    const unsigned bB = aB + 32768;
    const bool st = (tt + 1 < NT);

    if (st) {
      const int kt1 = (tt + 1) * 64;
#pragma unroll
      for (int u = 0; u < 4; ++u) stage_unit(Ag, K, bm, kt1, oth, u, t);
#pragma unroll
      for (int u = 0; u < NR; ++u) stage_unit(Bg, K, bn, kt1, oth + 32768, u, t);
    }

    short8 a[8][2], b[NR][2];
#pragma unroll
    for (int mf = 0; mf < 4; ++mf)
#pragma unroll
      for (int ks = 0; ks < 2; ++ks)
        a[mf][ks] = ds_read128(aB + aRow0 + mf * 2048 + (((unsigned)(ks * 64) + kb0) ^ x16));
#pragma unroll
    for (int nf = 0; nf < 2; ++nf)
#pragma unroll
      for (int ks = 0; ks < 2; ++ks)
        b[nf][ks] = ds_read128(bB + bRow0 + nf * 2048 + (((unsigned)(ks * 64) + kb0) ^ x16));
#pragma unroll
    for (int mf = 4; mf < 8; ++mf)
#pragma unroll
      for (int ks = 0; ks < 2; ++ks)
        a[mf][ks] = ds_read128(aB + aRow0 + mf * 2048 + (((unsigned)(ks * 64) + kb0) ^ x16));
#pragma unroll
    for (int nf = 2; nf < NR; ++nf)
#pragma unroll
      for (int ks = 0; ks < 2; ++ks)
        b[nf][ks] = ds_read128(bB + bRow0 + nf * 2048 + (((unsigned)(ks * 64) + kb0) ^ x16));

    if constexpr (NR == 4) WAITLG(12); else WAITLG(10);
    MFMA_BLK(0, 4, 0, 2);
    if constexpr (NR == 4) WAITLG(4);  else WAITLG(2);
    MFMA_BLK(4, 8, 0, 2);
    WAITLG(0);
    MFMA_BLK(0, 8, 2, NR);

    if (st) WAITV0();
    BAR();
    cur ^= 1;
  }
}

// in-proj GEMM (BN=192, N=4416 exact): routed epilogue
__global__ __launch_bounds__(512, 2)
void gemm_in256(const bf16* __restrict__ A, const bf16* __restrict__ Bw,
                const float* __restrict__ bias, bf16* __restrict__ x_bf,
                bf16* __restrict__ B_bf, bf16* __restrict__ C_bf, float* __restrict__ dtraw) {
  __shared__ char lds[2 * (32768 + 3 * 8192)];
  int nwg = gridDim.x, bid = blockIdx.x;
  int cpx = nwg >> 3;
  int sb = (bid & 7) * cpx + (bid >> 3);       // bijective: nwg % 8 == 0
  int bx = sb % (IN_PROJ / 192), by = sb / (IN_PROJ / 192);
  int bm = by * 256, bn = bx * 192;
  f32x4 acc[8][3] = {};
  gemm_core1<192>(A, Bw, MODEL_DIM, MODEL_DIM / 64, bm, bn, lds, acc);
  const int lane = threadIdx.x & 63, wid = threadIdx.x >> 6;
  const int wm = wid >> 2, wn = wid & 3;
#pragma unroll
  for (int mf = 0; mf < 8; ++mf)
#pragma unroll
    for (int nf = 0; nf < 3; ++nf)
#pragma unroll
      for (int r = 0; r < 4; ++r) {
        int row = bm + wm * 128 + mf * 16 + (lane >> 4) * 4 + r;
        int col = bn + wn * 48 + nf * 16 + (lane & 15);
        float v = acc[mf][nf][r] + bias[col];
        if (col < 4096)       x_bf[(size_t)row * 4096 + col]         = __float2bfloat16(v);
        else if (col < 4224)  B_bf[(size_t)row * 128 + (col - 4096)] = __float2bfloat16(v);
        else if (col < 4352)  C_bf[(size_t)row * 128 + (col - 4224)] = __float2bfloat16(v);
        else                  dtraw[(size_t)row * 64 + (col - 4352)] = v;
      }
}

// out-proj GEMM (BN=256): f32 output + bias
__global__ __launch_bounds__(512, 2)
void gemm_out256(const bf16* __restrict__ A, const bf16* __restrict__ Bw,
                 const float* __restrict__ bias, float* __restrict__ C) {
  __shared__ char lds[2 * (32768 + 4 * 8192)];
  int nwg = gridDim.x, bid = blockIdx.x;
  int cpx = nwg >> 3;
  int sb = (bid & 7) * cpx + (bid >> 3);
  int bx = sb % (MODEL_DIM / 256), by = sb / (MODEL_DIM / 256);
  int bm = by * 256, bn = bx * 256;
  f32x4 acc[8][4] = {};
  gemm_core1<256>(A, Bw, INNER, INNER / 64, bm, bn, lds, acc);
  const int lane = threadIdx.x & 63, wid = threadIdx.x >> 6;
  const int wm = wid >> 2, wn = wid & 3;
#pragma unroll
  for (int mf = 0; mf < 8; ++mf)
#pragma unroll
    for (int nf = 0; nf < 4; ++nf)
#pragma unroll
      for (int r = 0; r < 4; ++r) {
        int row = bm + wm * 128 + mf * 16 + (lane >> 4) * 4 + r;
        int col = bn + wn * 64 + nf * 16 + (lane & 15);
        C[(size_t)row * MODEL_DIM + col] = acc[mf][nf][r] + bias[col];
      }
}

// ---------------- converts ----------------
__global__ __launch_bounds__(256) void conv_f32_to_bf16(const float* __restrict__ src,
                                                        bf16* __restrict__ dst, int n4) {
  int i = blockIdx.x * 256 + threadIdx.x;
  if (i >= n4) return;
  float4 v = *(const float4*)(src + (size_t)i * 4);
  bf16* d = dst + (size_t)i * 4;
  d[0] = __float2bfloat16(v.x); d[1] = __float2bfloat16(v.y);
  d[2] = __float2bfloat16(v.z); d[3] = __float2bfloat16(v.w);
}

// ---------------- prep: dt tables only ----------------
__global__ __launch_bounds__(256)
void prep_small(const float* __restrict__ dtraw, const float* __restrict__ A_log,
                const float* __restrict__ dt_bias, float* __restrict__ dts,
                float* __restrict__ a_dt) {
  int i = blockIdx.x * 256 + threadIdx.x;      // NTOK*64
  int h = i & 63;
  float z = dtraw[i] + dt_bias[h];
  float dt = (z > 20.f) ? z : log1pf(expf(z));
  dts[i] = dt;
  a_dt[i] = -expf(A_log[h]) * dt;
}

// ---------------- g_pre: G = C * B^T per (b,c), head-independent ----------------
__global__ __launch_bounds__(256)
void g_pre_kernel(const bf16* __restrict__ B_bf, const bf16* __restrict__ C_bf,
                  float* __restrict__ G_g) {
  __shared__ bf16 Cs[64 * 128];
  __shared__ bf16 Bs[64 * 128];
  int blk = blockIdx.x;             // b*64 + c
  int t = threadIdx.x, lane = t & 63, wid = t >> 6;
  int tokBase = (blk >> 6) * SEQ + (blk & 63) * 64;

#pragma unroll
  for (int i = 0; i < 4; ++i) {
    int chunk = t + i * 256;
    int l = chunk >> 4, n0 = (chunk & 15) * 8;
    *(short8*)(Cs + l * 128 + n0) = *(const short8*)(C_bf + (size_t)(tokBase + l) * 128 + n0);
    *(short8*)(Bs + l * 128 + n0) = *(const short8*)(B_bf + (size_t)(tokBase + l) * 128 + n0);
  }
  __syncthreads();

  int lBase = (wid >> 1) * 32, sBase = (wid & 1) * 32;
  f32x4 g[2][2] = {};
#pragma unroll
  for (int ks = 0; ks < 4; ++ks) {
    short8 a[2], bb[2];
#pragma unroll
    for (int mi = 0; mi < 2; ++mi)
      a[mi] = *(const short8*)(Cs + (lBase + mi * 16 + (lane & 15)) * 128 + ks * 32 + (lane >> 4) * 8);
#pragma unroll
    for (int ni = 0; ni < 2; ++ni)
      bb[ni] = *(const short8*)(Bs + (sBase + ni * 16 + (lane & 15)) * 128 + ks * 32 + (lane >> 4) * 8);
#pragma unroll
    for (int mi = 0; mi < 2; ++mi)
#pragma unroll
      for (int ni = 0; ni < 2; ++ni)
        g[mi][ni] = __builtin_amdgcn_mfma_f32_16x16x32_bf16(a[mi], bb[ni], g[mi][ni], 0, 0, 0);
  }
  float* Gd = G_g + (size_t)blk * 4096;
#pragma unroll
  for (int mi = 0; mi < 2; ++mi)
#pragma unroll
    for (int ni = 0; ni < 2; ++ni)
#pragma unroll
      for (int r = 0; r < 4; ++r) {
        int row = lBase + mi * 16 + (lane >> 4) * 4 + r;
        int col = sBase + ni * 16 + (lane & 15);
        Gd[row * 64 + col] = g[mi][ni][r];
      }
}

// ---------------- FUSED intra-chunk states + inter-chunk scan (1-sync pipeline) ----------------
#define LP 72   /* padded LDS row length */
__global__ __launch_bounds__(256)
void ssd_fused_kernel(const bf16* __restrict__ x_bf, const bf16* __restrict__ B_bf,
                      const float* __restrict__ dts_g, const float* __restrict__ a_dt,
                      float* __restrict__ acs_g, bf16* __restrict__ states_g,
                      float* __restrict__ out_fs) {
  __shared__ bf16 xT[2][32 * LP];
  __shared__ bf16 BT[2][128 * LP];
  __shared__ float sc_s[2][64];     // dt*decay scale per token; ring by chunk parity (pre-phase only)
  __shared__ float dfac_s[4];       // depth-4 ring: pre(c) write crosses to post(c) read
  int blk = blockIdx.x;
  int pg = blk & 1, h = (blk >> 1) & 63, b = blk >> 7;
  int t = threadIdx.x, lane = t & 63, w = t >> 6;
  int lx = t >> 2, sx = t & 3;

  f32x4 S4[4] = {};
  short8 rxC, rBC[4], rxN, rBN[4];
  float raN = 0.f, rdtN = 0.f;

  // prologue: chunk 0 data + cumsum(0); chunk 1 data
  {
    int tb = b * SEQ;
    rxC = *(const short8*)(x_bf + (size_t)(tb + lx) * 4096 + h * 64 + pg * 32 + sx * 8);
#pragma unroll
    for (int k = 0; k < 4; ++k)
      rBC[k] = *(const short8*)(B_bf + (size_t)(tb + lx) * 128 + sx * 32 + k * 8);
    if (t < 64) {
      float ra0 = a_dt[(size_t)(tb + t) * 64 + h];
      float rdt0 = dts_g[(size_t)(tb + t) * 64 + h];
      float v = ra0;
#pragma unroll
      for (int d = 1; d < 64; d <<= 1) { float o = __shfl_up(v, d); if (t >= d) v += o; }
      float a63 = __shfl(v, 63);
      if (pg == 0) acs_g[(((size_t)(b * 64 + 0)) * 64 + h) * 64 + t] = v;
      sc_s[0][t] = rdt0 * expf(a63 - v);
      if (t == 0) dfac_s[0] = expf(a63);
    }
    int tb1 = tb + 64;
    rxN = *(const short8*)(x_bf + (size_t)(tb1 + lx) * 4096 + h * 64 + pg * 32 + sx * 8);
#pragma unroll
    for (int k = 0; k < 4; ++k)
      rBN[k] = *(const short8*)(B_bf + (size_t)(tb1 + lx) * 128 + sx * 32 + k * 8);
    if (t < 64) {
      raN = a_dt[(size_t)(tb1 + t) * 64 + h];
      rdtN = dts_g[(size_t)(tb1 + t) * 64 + h];
    }
  }
  __syncthreads();

  for (int c = 0; c < 64; ++c) {
    // issue loads for c+2 (clamped; unused duplicates at the tail)
    int c2 = (c < 62) ? c + 2 : 63;
    int tb2 = b * SEQ + c2 * 64;
    short8 rxI = *(const short8*)(x_bf + (size_t)(tb2 + lx) * 4096 + h * 64 + pg * 32 + sx * 8);
    short8 rBI[4];
#pragma unroll
    for (int k = 0; k < 4; ++k)
      rBI[k] = *(const short8*)(B_bf + (size_t)(tb2 + lx) * 128 + sx * 32 + k * 8);
    float raI = 0.f, rdtI = 0.f;
    if (t < 64) {
      raI = a_dt[(size_t)(tb2 + t) * 64 + h];
      rdtI = dts_g[(size_t)(tb2 + t) * 64 + h];
    }

    int bufc = c & 1;
    // pre: transpose(c) with sc_s[c&1]; wave-0 lanes also cumsum(c+1)
    {
      float s_l = sc_s[bufc][lx];
      const bf16* pv = (const bf16*)&rxC;
#pragma unroll
      for (int j = 0; j < 8; ++j)
        xT[bufc][(sx * 8 + j) * LP + lx] = __float2bfloat16(__bfloat162float(pv[j]) * s_l);
#pragma unroll
      for (int k = 0; k < 4; ++k) {
        const bf16* pb = (const bf16*)&rBC[k];
        int n0 = sx * 32 + k * 8;
#pragma unroll
        for (int j = 0; j < 8; ++j) BT[bufc][(n0 + j) * LP + lx] = pb[j];
      }
    }
    if (t < 64) {
      float v = raN;
#pragma unroll
      for (int d = 1; d < 64; d <<= 1) { float o = __shfl_up(v, d); if (t >= d) v += o; }
      float a63 = __shfl(v, 63);
      if (c + 1 < 64 && pg == 0)
        acs_g[(((size_t)(b * 64 + c + 1)) * 64 + h) * 64 + t] = v;
      sc_s[(c + 1) & 1][t] = rdtN * expf(a63 - v);
      if (t == 0) dfac_s[(c + 1) & 3] = expf(a63);
    }
    __syncthreads();

    // post: MFMA(c) + in-register scan + states write
    float dfac = dfac_s[c & 3];
    int ps = (w >> 1) * 16, nb = (w & 1) * 64;
    f32x4 acc[4] = {};
    short8 af[2];
#pragma unroll
    for (int ks = 0; ks < 2; ++ks)
      af[ks] = *(const short8*)(&xT[bufc][(ps + (lane & 15)) * LP + ks * 32 + (lane >> 4) * 8]);
#pragma unroll
    for (int nf = 0; nf < 4; ++nf)
#pragma unroll
      for (int ks = 0; ks < 2; ++ks) {
        short8 bf_ = *(const short8*)(&BT[bufc][(nb + nf * 16 + (lane & 15)) * LP + ks * 32 + (lane >> 4) * 8]);
        acc[nf] = __builtin_amdgcn_mfma_f32_16x16x32_bf16(af[ks], bf_, acc[nf], 0, 0, 0);
      }
    size_t sbase = ((size_t)((b * 64 + c) * 64 + h)) * 8192;
#pragma unroll
    for (int nf = 0; nf < 4; ++nf)
#pragma unroll
      for (int r = 0; r < 4; ++r) {
        int p = pg * 32 + ps + (lane >> 4) * 4 + r;
        int n = nb + nf * 16 + (lane & 15);
        states_g[sbase + (size_t)p * 128 + n] = __float2bfloat16(S4[nf][r]);
        S4[nf][r] = dfac * S4[nf][r] + acc[nf][r];
      }

    rxC = rxN; rxN = rxI;
#pragma unroll
    for (int k = 0; k < 4; ++k) { rBC[k] = rBN[k]; rBN[k] = rBI[k]; }
    raN = raI; rdtN = rdtI;
  }

  size_t ob = ((size_t)(b * 64 + h)) * 8192;
  int ps = (w >> 1) * 16, nb = (w & 1) * 64;
#pragma unroll
  for (int nf = 0; nf < 4; ++nf)
#pragma unroll
    for (int r = 0; r < 4; ++r) {
      int p = pg * 32 + ps + (lane >> 4) * 4 + r;
      int n = nb + nf * 16 + (lane & 15);
      out_fs[ob + (size_t)p * 128 + n] = S4[nf][r];
    }
}

// ---------------- output: 4 heads per block; C + G staged/loaded once ----------------
__global__ __launch_bounds__(256)
void ssd_out_kernel(bf16* __restrict__ x_bf, const bf16* __restrict__ C_bf,
                    const float* __restrict__ dts, const float* __restrict__ acs_g,
                    const bf16* __restrict__ states_g, const float* __restrict__ G_g) {
  __shared__ bf16 Cs[64 * 128];     // [l][n] (head-independent)
  __shared__ bf16 Ms[64 * 64];      // masked scores [l][s]
  __shared__ bf16 xT[64 * 64];      // [p][l]
  __shared__ bf16 Sp[64 * 128];     // [p][n]
  __shared__ float acs_s[2][64];    // double-buffered by head parity
  int blk = blockIdx.x;             // (b*64 + c)*16 + hg
  int hg = blk & 15, c = (blk >> 4) & 63, b = blk >> 10;
  int t = threadIdx.x, lane = t & 63, wid = t >> 6;
  int tokBase = b * SEQ + c * 64;

  int lBase = (wid >> 1) * 32, sBase = (wid & 1) * 32;
  // G: head-independent — load once
  const float* Gd = G_g + ((size_t)(b * 64 + c)) * 4096;
  float gv[2][2][4];
#pragma unroll
  for (int mi = 0; mi < 2; ++mi)
#pragma unroll
    for (int ni = 0; ni < 2; ++ni)
#pragma unroll
      for (int r = 0; r < 4; ++r)
        gv[mi][ni][r] = Gd[(lBase + mi * 16 + (lane >> 4) * 4 + r) * 64 +
                           sBase + ni * 16 + (lane & 15)];

  // C: head-independent — stage once
#pragma unroll
  for (int i = 0; i < 4; ++i) {
    int chunk = t + i * 256;
    int l = chunk >> 4, n0 = (chunk & 15) * 8;
    *(short8*)(Cs + l * 128 + n0) = *(const short8*)(C_bf + (size_t)(tokBase + l) * 128 + n0);
  }

  for (int hi = 0; hi < 4; ++hi) {
    int h = hg * 4 + hi;
    size_t sbase = ((size_t)((b * 64 + c) * 64 + h)) * 8192;

    // stage head-specific: acs, xT (dt-scaled), Sp
    if (t < 64) acs_s[hi & 1][t] = acs_g[(((size_t)(b * 64 + c)) * 64 + h) * 64 + t];
#pragma unroll
    for (int i = 0; i < 2; ++i) {
      int chunk = t + i * 256;
      int l = chunk >> 3, p0 = (chunk & 7) * 8;
      float dtv = dts[(size_t)(tokBase + l) * 64 + h];
      short8 vv = *(const short8*)(x_bf + (size_t)(tokBase + l) * 4096 + h * 64 + p0);
      const bf16* pv = (const bf16*)&vv;
#pragma unroll
      for (int j = 0; j < 8; ++j)
        xT[(p0 + j) * 64 + l] = __float2bfloat16(__bfloat162float(pv[j]) * dtv);
    }
#pragma unroll
    for (int i = 0; i < 4; ++i) {
      int chunk = t + i * 256;
      *(short8*)(Sp + chunk * 8) = *(const short8*)(states_g + sbase + chunk * 8);
    }
    __syncthreads();                 // sync_a: stages visible (covers Cs/G on hi==0)

    // masked scores from precomputed G
#pragma unroll
    for (int mi = 0; mi < 2; ++mi)
#pragma unroll
      for (int ni = 0; ni < 2; ++ni)
#pragma unroll
        for (int r = 0; r < 4; ++r) {
          int row = lBase + mi * 16 + (lane >> 4) * 4 + r;
          int col = sBase + ni * 16 + (lane & 15);
          float lm = (row >= col) ? expf(acs_s[hi & 1][row] - acs_s[hi & 1][col]) : 0.f;
          Ms[row * 64 + col] = __float2bfloat16(gv[mi][ni][r] * lm);
        }
    __syncthreads();                 // sync_b: Ms visible

    int pBase = (wid & 1) * 32;
    f32x4 yd[2][2] = {}, yo[2][2] = {};
#pragma unroll
    for (int ks = 0; ks < 2; ++ks) {
      short8 a[2], bb[2];
#pragma unroll
      for (int mi = 0; mi < 2; ++mi)
        a[mi] = *(const short8*)(Ms + (lBase + mi * 16 + (lane & 15)) * 64 + ks * 32 + (lane >> 4) * 8);
#pragma unroll
      for (int ni = 0; ni < 2; ++ni)
        bb[ni] = *(const short8*)(xT + (pBase + ni * 16 + (lane & 15)) * 64 + ks * 32 + (lane >> 4) * 8);
#pragma unroll
      for (int mi = 0; mi < 2; ++mi)
#pragma unroll
        for (int ni = 0; ni < 2; ++ni)
          yd[mi][ni] = __builtin_amdgcn_mfma_f32_16x16x32_bf16(a[mi], bb[ni], yd[mi][ni], 0, 0, 0);
    }
#pragma unroll
    for (int ks = 0; ks < 4; ++ks) {
      short8 a[2], bb[2];
#pragma unroll
      for (int mi = 0; mi < 2; ++mi)
        a[mi] = *(const short8*)(Cs + (lBase + mi * 16 + (lane & 15)) * 128 + ks * 32 + (lane >> 4) * 8);
#pragma unroll
      for (int ni = 0; ni < 2; ++ni)
        bb[ni] = *(const short8*)(Sp + (pBase + ni * 16 + (lane & 15)) * 128 + ks * 32 + (lane >> 4) * 8);
#pragma unroll
      for (int mi = 0; mi < 2; ++mi)
#pragma unroll
        for (int ni = 0; ni < 2; ++ni)
          yo[mi][ni] = __builtin_amdgcn_mfma_f32_16x16x32_bf16(a[mi], bb[ni], yo[mi][ni], 0, 0, 0);
    }
    __syncthreads();                 // sync_c: all LDS reads of this head done

    // write y in place (uses acs_s[hi&1]; next head stages acs_s[(hi+1)&1])
#pragma unroll
    for (int mi = 0; mi < 2; ++mi)
#pragma unroll
      for (int ni = 0; ni < 2; ++ni)
#pragma unroll
        for (int r = 0; r < 4; ++r) {
          int lr = lBase + mi * 16 + (lane >> 4) * 4 + r;
          int p = pBase + ni * 16 + (lane & 15);
          float val = yd[mi][ni][r] + expf(acs_s[hi & 1][lr]) * yo[mi][ni][r];
          x_bf[(size_t)(tokBase + lr) * 4096 + h * 64 + p] = __float2bfloat16(val);
        }
  }
}

// ---------------- launch ----------------
extern "C" void kernel_launch(void* const* d_in, const int* in_sizes, int n_in,
                              void* d_out, int out_size, void* d_ws, size_t ws_size,
                              hipStream_t stream) {
  const float* u       = (const float*)d_in[0];
  const float* W_in    = (const float*)d_in[1];
  const float* b_in    = (const float*)d_in[2];
  const float* W_out   = (const float*)d_in[3];
  const float* b_out   = (const float*)d_in[4];
  const float* A_log   = (const float*)d_in[5];
  const float* dt_bias = (const float*)d_in[6];

  float* y_out  = (float*)d_out;
  float* fs_out = y_out + (size_t)NTOK * MODEL_DIM;

  char* ws = (char*)d_ws;
  size_t off = 0;
  auto alloc = [&](size_t bytes) { char* p = ws + off; off += (bytes + 255) & ~255ull; return p; };
  bf16*  wout_bf = (bf16*) alloc((size_t)MODEL_DIM * INNER * 2);   // 16.8 MB
  bf16*  x_bf    = (bf16*) alloc((size_t)NTOK * INNER * 2);        // 67 MB (x, then y)
  bf16*  B_bf    = (bf16*) alloc((size_t)NTOK * STATE_DIM * 2);
  bf16*  C_bf    = (bf16*) alloc((size_t)NTOK * STATE_DIM * 2);
  float* dtraw   = (float*)alloc((size_t)NTOK * NHEADS * 4);
  float* dts     = (float*)alloc((size_t)NTOK * NHEADS * 4);
  float* a_dt    = (float*)alloc((size_t)NTOK * NHEADS * 4);
  float* acs     = (float*)alloc((size_t)BSZ * NCHUNK * NHEADS * 64 * 4);
  float* gbuf    = (float*)alloc((size_t)BSZ * NCHUNK * 4096 * 4); // 2 MB
  // region Q: states (bf16, 134 MB) aliased with {u_bf, win_bf} (dead after gemm_in)
  char*  Q       = alloc((size_t)BSZ * NCHUNK * NHEADS * 64 * 128 * 2);
  bf16*  states  = (bf16*)Q;
  bf16*  u_bf    = (bf16*)Q;
  bf16*  win_bf  = u_bf + (size_t)NTOK * MODEL_DIM;
  (void)ws_size; (void)off; (void)in_sizes; (void)n_in; (void)out_size;

  conv_f32_to_bf16<<<dim3(16384), dim3(256), 0, stream>>>(u, u_bf, NTOK * MODEL_DIM / 4);
  conv_f32_to_bf16<<<dim3(IN_PROJ * MODEL_DIM / 1024), dim3(256), 0, stream>>>(
      W_in, win_bf, IN_PROJ * MODEL_DIM / 4);
  conv_f32_to_bf16<<<dim3(8192), dim3(256), 0, stream>>>(W_out, wout_bf, MODEL_DIM * INNER / 4);

  gemm_in256<<<dim3((NTOK / 256) * (IN_PROJ / 192)), dim3(512), 0, stream>>>(
      u_bf, win_bf, b_in, x_bf, B_bf, C_bf, dtraw);

  prep_small<<<dim3(NTOK * NHEADS / 256), dim3(256), 0, stream>>>(dtraw, A_log, dt_bias, dts, a_dt);

  g_pre_kernel<<<dim3(BSZ * NCHUNK), dim3(256), 0, stream>>>(B_bf, C_bf, gbuf);

  ssd_fused_kernel<<<dim3(BSZ * NHEADS * 2), dim3(256), 0, stream>>>(
      x_bf, B_bf, dts, a_dt, acs, states, fs_out);

  ssd_out_kernel<<<dim3(BSZ * NCHUNK * 16), dim3(256), 0, stream>>>(
      x_bf, C_bf, dts, acs, states, gbuf);

  gemm_out256<<<dim3((MODEL_DIM / 256) * (NTOK / 256)), dim3(512), 0, stream>>>(
      x_bf, wout_bf, b_out, y_out);
}